// Round 8
// baseline (364.502 us; speedup 1.0000x reference)
//
#include <hip/hip_runtime.h>
#include <cstdint>
#include <cstddef>

#define HH 128
#define SLOPE 0.01f

typedef __attribute__((ext_vector_type(8))) __bf16 bf16x8;
typedef __attribute__((ext_vector_type(4))) float f32x4;

__device__ __forceinline__ float lrelu(float x) { return x >= 0.f ? x : SLOPE * x; }
__device__ __forceinline__ unsigned short f2b(float f) {
  union { float f; unsigned u; } v; v.f = f;
  unsigned r = v.u + 0x7fffu + ((v.u >> 16) & 1u);  // round-to-nearest-even
  return (unsigned short)(r >> 16);
}
__device__ __forceinline__ float b2f(unsigned short u) {
  union { unsigned u; float f; } v; v.u = ((unsigned)u) << 16; return v.f;
}

// ---------------- CSR build ----------------

__global__ __launch_bounds__(256) void count_kernel(const int* __restrict__ dst,
                                                    int* __restrict__ cnt, int nE) {
  int e = blockIdx.x * 256 + threadIdx.x;
  if (e < nE) atomicAdd(&cnt[dst[e]], 1);
}

// phase 1: per-block scan; also dinv = rsqrt(cnt+1) and cnt reset (cursor for fill)
__global__ __launch_bounds__(1024) void scan1_kernel(int* __restrict__ cnt,
                                                     int* __restrict__ rowptr,
                                                     int* __restrict__ bsum,
                                                     float* __restrict__ dinv, int n) {
  __shared__ int wsum[16];
  const int tid = threadIdx.x;
  const int lane = tid & 63, wid = tid >> 6;
  int i = blockIdx.x * 1024 + tid;
  int v = (i < n) ? cnt[i] : 0;
  int x = v;
#pragma unroll
  for (int off = 1; off < 64; off <<= 1) {
    int y = __shfl_up(x, off, 64);
    if (lane >= off) x += y;
  }
  if (lane == 63) wsum[wid] = x;
  __syncthreads();
  if (tid == 0) {
    int s = 0;
#pragma unroll
    for (int w = 0; w < 16; ++w) { int t = wsum[w]; wsum[w] = s; s += t; }
    bsum[blockIdx.x] = s;
  }
  __syncthreads();
  if (i < n) {
    rowptr[i] = wsum[wid] + x - v;  // local exclusive
    dinv[i] = rsqrtf((float)v + 1.0f);
    cnt[i] = 0;
  }
}

// phase 2: one wave scans the (<=64) block sums in place (exclusive); rowptr[n] = E
__global__ __launch_bounds__(64) void scan2_kernel(int* __restrict__ bsum, int nb,
                                                   int* __restrict__ rowptr, int n, int E) {
  int lane = threadIdx.x;
  int v = (lane < nb) ? bsum[lane] : 0;
  int x = v;
#pragma unroll
  for (int off = 1; off < 64; off <<= 1) {
    int y = __shfl_up(x, off, 64);
    if (lane >= off) x += y;
  }
  if (lane < nb) bsum[lane] = x - v;  // exclusive
  if (lane == 0) rowptr[n] = E;
}

// phase 3: add block offset
__global__ __launch_bounds__(1024) void scan3_kernel(int* __restrict__ rowptr,
                                                     const int* __restrict__ bsum, int n) {
  int i = blockIdx.x * 1024 + threadIdx.x;
  if (i < n) rowptr[i] += bsum[blockIdx.x];
}

__global__ __launch_bounds__(256) void fill_kernel(const int* __restrict__ src,
                                                   const int* __restrict__ dst,
                                                   const int* __restrict__ rowptr,
                                                   int* __restrict__ cursor,
                                                   const float* __restrict__ dinv,
                                                   int* __restrict__ csr_src,
                                                   float* __restrict__ csr_norm, int nE) {
  int e = blockIdx.x * 256 + threadIdx.x;
  if (e >= nE) return;
  int d = dst[e], s = src[e];
  int pos = rowptr[d] + atomicAdd(&cursor[d], 1);
  csr_src[pos] = s;
  csr_norm[pos] = dinv[s] * dinv[d];
}

// ---------------- weight pack: B-fragment order for mfma 16x16x32 ----------------
// packed[(t*8+c)*64 + lane][j] = W[t*32 + (lane>>4)*8 + j][c*16 + (lane&15)]

__global__ __launch_bounds__(256) void pack_kernel(const float* W0, const float* W1,
                                                   const float* W2, const float* W3,
                                                   const float* W4, const float* W5,
                                                   unsigned short* __restrict__ out) {
  const float* Ws[6] = {W0, W1, W2, W3, W4, W5};
  const float* W = Ws[blockIdx.y];
  int f = blockIdx.x * 256 + threadIdx.x;  // 0..16383
  int j = f & 7, L = (f >> 3) & 63, c = (f >> 9) & 7, t = f >> 12;
  int k = t * 32 + (L >> 4) * 8 + j;
  int n = c * 16 + (L & 15);
  out[(size_t)blockIdx.y * 16384 + f] = f2b(W[k * HH + n]);
}

// ---------------- shared device helpers ----------------

__device__ __forceinline__ void mfma_stage(const unsigned short* __restrict__ Alds,
                                           const bf16x8* __restrict__ Wf,
                                           int arow, int lane, int quad, f32x4* acc) {
#pragma unroll
  for (int c = 0; c < 8; ++c) acc[c] = (f32x4){0.f, 0.f, 0.f, 0.f};
#pragma unroll
  for (int t = 0; t < 4; ++t) {
    bf16x8 a = *(const bf16x8*)&Alds[arow * HH + t * 32 + quad * 8];
#pragma unroll
    for (int c = 0; c < 8; ++c)
      acc[c] = __builtin_amdgcn_mfma_f32_16x16x32_bf16(a, Wf[(t * 8 + c) * 64 + lane], acc[c], 0, 0, 0);
  }
}

__device__ __forceinline__ void gather_node(const unsigned short* __restrict__ h,
                                            const int* __restrict__ csr_src,
                                            const float* __restrict__ csr_norm,
                                            int beg, int end, int c,
                                            float& ax, float& ay) {
  int j = beg;
  for (; j + 4 <= end; j += 4) {
    int s0 = csr_src[j], s1 = csr_src[j + 1], s2 = csr_src[j + 2], s3 = csr_src[j + 3];
    float n0 = csr_norm[j], n1 = csr_norm[j + 1], n2 = csr_norm[j + 2], n3 = csr_norm[j + 3];
    ushort2 r0 = *(const ushort2*)(h + (size_t)s0 * HH + c);
    ushort2 r1 = *(const ushort2*)(h + (size_t)s1 * HH + c);
    ushort2 r2 = *(const ushort2*)(h + (size_t)s2 * HH + c);
    ushort2 r3 = *(const ushort2*)(h + (size_t)s3 * HH + c);
    ax = fmaf(b2f(r0.x), n0, ax); ay = fmaf(b2f(r0.y), n0, ay);
    ax = fmaf(b2f(r1.x), n1, ax); ay = fmaf(b2f(r1.y), n1, ay);
    ax = fmaf(b2f(r2.x), n2, ax); ay = fmaf(b2f(r2.y), n2, ay);
    ax = fmaf(b2f(r3.x), n3, ax); ay = fmaf(b2f(r3.y), n3, ay);
  }
  for (; j < end; ++j) {
    int s0 = csr_src[j];
    float n0 = csr_norm[j];
    ushort2 r0 = *(const ushort2*)(h + (size_t)s0 * HH + c);
    ax = fmaf(b2f(r0.x), n0, ax); ay = fmaf(b2f(r0.y), n0, ay);
  }
}

// ---------------- conv1 GEMM: x(fp32) @ Wc1 -> bf16 ----------------

__global__ __launch_bounds__(256) void gemm_conv1(const float* __restrict__ A,
                                                  const unsigned short* __restrict__ Wp,
                                                  unsigned short* __restrict__ out, int nrows) {
  __shared__ __align__(16) unsigned short Al[64 * HH];
  const int tid = threadIdx.x;
  const int row0 = blockIdx.x * 64;

  for (int i = tid; i < 2048; i += 256) {
    int r = i >> 5, c = (i & 31) << 2;
    int gr = row0 + r;
    float4 v = make_float4(0.f, 0.f, 0.f, 0.f);
    if (gr < nrows) v = *(const float4*)(A + (size_t)gr * HH + c);
    ushort4 o;
    o.x = f2b(v.x); o.y = f2b(v.y); o.z = f2b(v.z); o.w = f2b(v.w);
    *(ushort4*)&Al[r * HH + c] = o;
  }
  __syncthreads();

  const int lane = tid & 63, wave = tid >> 6;
  const int m = lane & 15, quad = lane >> 4;
  const int arow = wave * 16 + m;

  f32x4 acc[8];
  mfma_stage(Al, (const bf16x8*)Wp, arow, lane, quad, acc);

#pragma unroll
  for (int c = 0; c < 8; ++c) {
    int col = c * 16 + m;
#pragma unroll
    for (int g = 0; g < 4; ++g) {
      int row = row0 + wave * 16 + quad * 4 + g;
      if (row < nrows) out[(size_t)row * HH + col] = f2b(acc[c][g]);
    }
  }
}

// ---------------- fusedA: agg1(+bc1,leaky) -> f1(FP32 global + bf16 LDS) ; f1 @ Wc2 -> t2(bf16) ----
// NOTE: __syncthreads() between the LDS-write (agg) phase and the MFMA reads is
// REQUIRED: the MFMA fragment reads consume bytes written by OTHER lanes; without
// a barrier that cross-lane LDS RAW is a compiler-visible data race (r6/r7 failure).

__global__ __launch_bounds__(256) void fusedA(const unsigned short* __restrict__ h,
                                              const int* __restrict__ rowptr,
                                              const int* __restrict__ csr_src,
                                              const float* __restrict__ csr_norm,
                                              const float* __restrict__ dinv,
                                              const float* __restrict__ bias,
                                              const unsigned short* __restrict__ Wp,
                                              float* __restrict__ f1_out,
                                              unsigned short* __restrict__ t2_out, int n) {
  __shared__ __align__(16) unsigned short Al[64 * HH];
  const int tid = threadIdx.x;
  const int lane = tid & 63, wave = tid >> 6;
  const int row0 = blockIdx.x * 64;
  const int c = lane << 1;
  const float2 bv = *(const float2*)(bias + c);

  // ---- aggregation phase: 16 nodes per wave ----
  for (int i = 0; i < 16; ++i) {
    int lrow = wave * 16 + i;
    int node = row0 + lrow;
    ushort2 o = make_ushort2(0, 0);
    if (node < n) {
      float ax = 0.f, ay = 0.f;
      gather_node(h, csr_src, csr_norm, rowptr[node], rowptr[node + 1], c, ax, ay);
      float di = dinv[node], d2 = di * di;
      ushort2 hs = *(const ushort2*)(h + (size_t)node * HH + c);
      float ox = lrelu(ax + b2f(hs.x) * d2 + bv.x);
      float oy = lrelu(ay + b2f(hs.y) * d2 + bv.y);
      *(float2*)(f1_out + (size_t)node * HH + c) = make_float2(ox, oy);  // fp32 residual
      o.x = f2b(ox); o.y = f2b(oy);
    }
    *(ushort2*)&Al[lrow * HH + c] = o;
  }
  __syncthreads();

  // ---- GEMM phase ----
  const int m = lane & 15, quad = lane >> 4;
  const int arow = wave * 16 + m;
  f32x4 acc[8];
  mfma_stage(Al, (const bf16x8*)Wp, arow, lane, quad, acc);

#pragma unroll
  for (int cc = 0; cc < 8; ++cc) {
    int col = cc * 16 + m;
#pragma unroll
    for (int g = 0; g < 4; ++g) {
      int row = row0 + wave * 16 + quad * 4 + g;
      if (row < n) t2_out[(size_t)row * HH + col] = f2b(acc[cc][g]);
    }
  }
}

// ---------------- fusedB: agg2 -> MLP -> interp -> proj -> out ----------------
// f2 = leaky(agg(t2)+self+bc2+f1_fp32)  [fp32 -> f2scratch, bf16 -> Al]
// m  = leaky(f2@Wm1+bm1)                [bf16 -> Bl]
// h3 = leaky(m@Wm2+bm2+f2_fp32); p = 0.5*(h3+gen) [bf16 -> Al]
// q  = leaky(p@Wp1+bp1)                 [bf16 -> Bl]
// out= leaky(q@Wp2+bp2)                 [fp32 global]
// __syncthreads() after every write phase (see fusedA note).

__global__ __launch_bounds__(256) void fusedB(const unsigned short* __restrict__ t2,
                                              const int* __restrict__ rowptr,
                                              const int* __restrict__ csr_src,
                                              const float* __restrict__ csr_norm,
                                              const float* __restrict__ dinv,
                                              const float* __restrict__ bc2,
                                              const float* __restrict__ f1res,
                                              float* __restrict__ f2scratch,
                                              const unsigned short* __restrict__ Wm1p,
                                              const unsigned short* __restrict__ Wm2p,
                                              const unsigned short* __restrict__ Wp1p,
                                              const unsigned short* __restrict__ Wp2p,
                                              const float* __restrict__ bm1,
                                              const float* __restrict__ bm2,
                                              const float* __restrict__ bp1,
                                              const float* __restrict__ bp2,
                                              const float* __restrict__ gen,
                                              float* __restrict__ out, int n) {
  __shared__ __align__(16) unsigned short Al[64 * HH];
  __shared__ __align__(16) unsigned short Bl[64 * HH];
  const int tid = threadIdx.x;
  const int lane = tid & 63, wave = tid >> 6;
  const int row0 = blockIdx.x * 64;
  const int c = lane << 1;
  const float2 bv = *(const float2*)(bc2 + c);

  // ---- aggregation phase: f2 -> f2scratch (fp32) + Al (bf16) ----
  for (int i = 0; i < 16; ++i) {
    int lrow = wave * 16 + i;
    int node = row0 + lrow;
    ushort2 o = make_ushort2(0, 0);
    if (node < n) {
      float ax = 0.f, ay = 0.f;
      gather_node(t2, csr_src, csr_norm, rowptr[node], rowptr[node + 1], c, ax, ay);
      float di = dinv[node], d2 = di * di;
      ushort2 hs = *(const ushort2*)(t2 + (size_t)node * HH + c);
      float2 rs = *(const float2*)(f1res + (size_t)node * HH + c);
      float ox = lrelu(ax + b2f(hs.x) * d2 + bv.x + rs.x);
      float oy = lrelu(ay + b2f(hs.y) * d2 + bv.y + rs.y);
      *(float2*)(f2scratch + (size_t)node * HH + c) = make_float2(ox, oy);
      o.x = f2b(ox); o.y = f2b(oy);
    }
    *(ushort2*)&Al[lrow * HH + c] = o;
  }
  __syncthreads();  // LDS RAW + f2scratch vmcnt drain

  const int m = lane & 15, quad = lane >> 4;
  const int arow = wave * 16 + m;
  f32x4 acc[8];

  // ---- stage 1: m = leaky(f2@Wm1+bm1) -> Bl ----
  mfma_stage(Al, (const bf16x8*)Wm1p, arow, lane, quad, acc);
#pragma unroll
  for (int cc = 0; cc < 8; ++cc) {
    int col = cc * 16 + m;
    float b1 = bm1[col];
#pragma unroll
    for (int g = 0; g < 4; ++g) {
      int lrow = wave * 16 + quad * 4 + g;
      Bl[lrow * HH + col] = f2b(lrelu(acc[cc][g] + b1));
    }
  }
  __syncthreads();

  // ---- stage 2: h3 = leaky(m@Wm2+bm2+f2_fp32); p = 0.5*(h3+gen) -> Al ----
  mfma_stage(Bl, (const bf16x8*)Wm2p, arow, lane, quad, acc);
#pragma unroll
  for (int cc = 0; cc < 8; ++cc) {
    int col = cc * 16 + m;
    float b2 = bm2[col];
#pragma unroll
    for (int g = 0; g < 4; ++g) {
      int lrow = wave * 16 + quad * 4 + g;
      int row = row0 + lrow;
      float f2v = 0.f, gv = 0.f;
      if (row < n) {
        f2v = f2scratch[(size_t)row * HH + col];
        gv = gen[(size_t)row * HH + col];
      }
      float v = lrelu(acc[cc][g] + b2 + f2v);
      Al[lrow * HH + col] = f2b(0.5f * (v + gv));
    }
  }
  __syncthreads();

  // ---- stage 3: q = leaky(p@Wp1+bp1) -> Bl ----
  mfma_stage(Al, (const bf16x8*)Wp1p, arow, lane, quad, acc);
#pragma unroll
  for (int cc = 0; cc < 8; ++cc) {
    int col = cc * 16 + m;
    float b3 = bp1[col];
#pragma unroll
    for (int g = 0; g < 4; ++g) {
      int lrow = wave * 16 + quad * 4 + g;
      Bl[lrow * HH + col] = f2b(lrelu(acc[cc][g] + b3));
    }
  }
  __syncthreads();

  // ---- stage 4: out = leaky(q@Wp2+bp2) ----
  mfma_stage(Bl, (const bf16x8*)Wp2p, arow, lane, quad, acc);
#pragma unroll
  for (int cc = 0; cc < 8; ++cc) {
    int col = cc * 16 + m;
    float b4 = bp2[col];
#pragma unroll
    for (int g = 0; g < 4; ++g) {
      int row = row0 + wave * 16 + quad * 4 + g;
      if (row < n) out[(size_t)row * HH + col] = lrelu(acc[cc][g] + b4);
    }
  }
}

// ---------------- launcher ----------------

extern "C" void kernel_launch(void* const* d_in, const int* in_sizes, int n_in,
                              void* d_out, int out_size, void* d_ws, size_t ws_size,
                              hipStream_t stream) {
  const float* x   = (const float*)d_in[0];
  const int* ei    = (const int*)d_in[1];
  const float* gen = (const float*)d_in[2];
  const float* Wc1 = (const float*)d_in[3];
  const float* bc1 = (const float*)d_in[4];
  const float* Wc2 = (const float*)d_in[5];
  const float* bc2 = (const float*)d_in[6];
  const float* Wm1 = (const float*)d_in[7];
  const float* bm1 = (const float*)d_in[8];
  const float* Wm2 = (const float*)d_in[9];
  const float* bm2 = (const float*)d_in[10];
  const float* Wp1 = (const float*)d_in[11];
  const float* bp1 = (const float*)d_in[12];
  const float* Wp2 = (const float*)d_in[13];
  const float* bp2 = (const float*)d_in[14];

  const int N = in_sizes[0] / HH;
  const int E = in_sizes[1] / 2;
  const int* src = ei;
  const int* dst = ei + E;

  char* ws = (char*)d_ws;
  size_t off = 0;
  auto alloc = [&](size_t bytes) { void* p = ws + off; off += (bytes + 255) & ~(size_t)255; return p; };
  float* dinv            = (float*)alloc((size_t)N * 4);
  int*   rowptr          = (int*)  alloc((size_t)(N + 1) * 4);
  int*   cursor          = (int*)  alloc((size_t)N * 4);
  int*   bsum            = (int*)  alloc((size_t)64 * 4);
  int*   csr_src         = (int*)  alloc((size_t)E * 4);
  float* csr_norm        = (float*)alloc((size_t)E * 4);
  unsigned short* h_bf   = (unsigned short*)alloc((size_t)N * HH * 2);
  unsigned short* t2_bf  = (unsigned short*)alloc((size_t)N * HH * 2);
  float* f1_f32          = (float*)alloc((size_t)N * HH * 4);
  float* f2_f32          = (float*)alloc((size_t)N * HH * 4);
  unsigned short* packed = (unsigned short*)alloc((size_t)6 * 16384 * 2);
  float* fOut = (float*)d_out;

  const int gblocks = (N + 63) / 64;
  const int eblocks = (E + 255) / 256;
  const int sblocks = (N + 1023) / 1024;  // <= 64 for N <= 65536

  // weight packing
  pack_kernel<<<dim3(64, 6), 256, 0, stream>>>(Wc1, Wc2, Wm1, Wm2, Wp1, Wp2, packed);

  // CSR build
  hipMemsetAsync(cursor, 0, (size_t)N * 4, stream);
  count_kernel<<<eblocks, 256, 0, stream>>>(dst, cursor, E);
  scan1_kernel<<<sblocks, 1024, 0, stream>>>(cursor, rowptr, bsum, dinv, N);
  scan2_kernel<<<1, 64, 0, stream>>>(bsum, sblocks, rowptr, N, E);
  scan3_kernel<<<sblocks, 1024, 0, stream>>>(rowptr, bsum, N);
  fill_kernel<<<eblocks, 256, 0, stream>>>(src, dst, rowptr, cursor, dinv, csr_src, csr_norm, E);

  // conv1 GEMM: h_bf = bf16(x @ Wc1)
  gemm_conv1<<<gblocks, 256, 0, stream>>>(x, packed + 0 * 16384, h_bf, N);

  // fusedA: f1 = leaky(agg(h_bf)+self+bc1) [fp32 + LDS bf16]; t2 = bf16(f1 @ Wc2)
  fusedA<<<gblocks, 256, 0, stream>>>(h_bf, rowptr, csr_src, csr_norm, dinv, bc1,
                                      packed + 1 * 16384, f1_f32, t2_bf, N);

  // fusedB: agg2(+f1 fp32) + MLP(+f2 fp32 res) + interp + proj -> d_out
  fusedB<<<gblocks, 256, 0, stream>>>(t2_bf, rowptr, csr_src, csr_norm, dinv, bc2,
                                      f1_f32, f2_f32,
                                      packed + 2 * 16384, packed + 3 * 16384,
                                      packed + 4 * 16384, packed + 5 * 16384,
                                      bm1, bm2, bp1, bp2, gen, fOut, N);
}

// Round 9
// 336.514 us; speedup vs baseline: 1.0832x; 1.0832x over previous
//
#include <hip/hip_runtime.h>
#include <cstdint>
#include <cstddef>

#define HH 128
#define SLOPE 0.01f

typedef __attribute__((ext_vector_type(8))) __bf16 bf16x8;
typedef __attribute__((ext_vector_type(4))) float f32x4;

__device__ __forceinline__ float lrelu(float x) { return x >= 0.f ? x : SLOPE * x; }
__device__ __forceinline__ unsigned short f2b(float f) {
  union { float f; unsigned u; } v; v.f = f;
  unsigned r = v.u + 0x7fffu + ((v.u >> 16) & 1u);  // round-to-nearest-even
  return (unsigned short)(r >> 16);
}
__device__ __forceinline__ float b2f(unsigned short u) {
  union { unsigned u; float f; } v; v.u = ((unsigned)u) << 16; return v.f;
}

// LDS tile layout with XOR swizzle: element (r,k) of a 64x128 bf16 tile lives at
// lofs(r,k). 16B chunks (8 ushorts) stay contiguous; chunk index ^= (r&15).
// Kills the 16-way ds_read_b128 bank conflict (row stride 256B == 0 mod 128B).
__device__ __forceinline__ int lofs(int r, int k) {
  return (r << 7) + ((((k >> 3) ^ r) & 15) << 3) + (k & 7);
}

// ---------------- CSR build ----------------

__global__ __launch_bounds__(256) void count_kernel(const int* __restrict__ dst,
                                                    int* __restrict__ cnt, int nE) {
  int e = blockIdx.x * 256 + threadIdx.x;
  if (e < nE) atomicAdd(&cnt[dst[e]], 1);
}

__global__ __launch_bounds__(1024) void scan1_kernel(int* __restrict__ cnt,
                                                     int* __restrict__ rowptr,
                                                     int* __restrict__ bsum,
                                                     float* __restrict__ dinv, int n) {
  __shared__ int wsum[16];
  const int tid = threadIdx.x;
  const int lane = tid & 63, wid = tid >> 6;
  int i = blockIdx.x * 1024 + tid;
  int v = (i < n) ? cnt[i] : 0;
  int x = v;
#pragma unroll
  for (int off = 1; off < 64; off <<= 1) {
    int y = __shfl_up(x, off, 64);
    if (lane >= off) x += y;
  }
  if (lane == 63) wsum[wid] = x;
  __syncthreads();
  if (tid == 0) {
    int s = 0;
#pragma unroll
    for (int w = 0; w < 16; ++w) { int t = wsum[w]; wsum[w] = s; s += t; }
    bsum[blockIdx.x] = s;
  }
  __syncthreads();
  if (i < n) {
    rowptr[i] = wsum[wid] + x - v;  // local exclusive
    dinv[i] = rsqrtf((float)v + 1.0f);
    cnt[i] = 0;
  }
}

__global__ __launch_bounds__(64) void scan2_kernel(int* __restrict__ bsum, int nb,
                                                   int* __restrict__ rowptr, int n, int E) {
  int lane = threadIdx.x;
  int v = (lane < nb) ? bsum[lane] : 0;
  int x = v;
#pragma unroll
  for (int off = 1; off < 64; off <<= 1) {
    int y = __shfl_up(x, off, 64);
    if (lane >= off) x += y;
  }
  if (lane < nb) bsum[lane] = x - v;  // exclusive
  if (lane == 0) rowptr[n] = E;
}

__global__ __launch_bounds__(1024) void scan3_kernel(int* __restrict__ rowptr,
                                                     const int* __restrict__ bsum, int n) {
  int i = blockIdx.x * 1024 + threadIdx.x;
  if (i < n) rowptr[i] += bsum[blockIdx.x];
}

// csr entry: .x = src node, .y = norm (float bits) — one 8B load per edge on gather
__global__ __launch_bounds__(256) void fill_kernel(const int* __restrict__ src,
                                                   const int* __restrict__ dst,
                                                   const int* __restrict__ rowptr,
                                                   int* __restrict__ cursor,
                                                   const float* __restrict__ dinv,
                                                   int2* __restrict__ csr, int nE) {
  int e = blockIdx.x * 256 + threadIdx.x;
  if (e >= nE) return;
  int d = dst[e], s = src[e];
  int pos = rowptr[d] + atomicAdd(&cursor[d], 1);
  int2 ent;
  ent.x = s;
  ent.y = __float_as_int(dinv[s] * dinv[d]);
  csr[pos] = ent;
}

// ---------------- weight pack: B-fragment order for mfma 16x16x32 ----------------
// packed[(t*8+c)*64 + lane][j] = W[t*32 + (lane>>4)*8 + j][c*16 + (lane&15)]

__global__ __launch_bounds__(256) void pack_kernel(const float* W0, const float* W1,
                                                   const float* W2, const float* W3,
                                                   const float* W4, const float* W5,
                                                   unsigned short* __restrict__ out) {
  const float* Ws[6] = {W0, W1, W2, W3, W4, W5};
  const float* W = Ws[blockIdx.y];
  int f = blockIdx.x * 256 + threadIdx.x;  // 0..16383
  int j = f & 7, L = (f >> 3) & 63, c = (f >> 9) & 7, t = f >> 12;
  int k = t * 32 + (L >> 4) * 8 + j;
  int n = c * 16 + (L & 15);
  out[(size_t)blockIdx.y * 16384 + f] = f2b(W[k * HH + n]);
}

// ---------------- shared device helpers ----------------

// acc = (16 rows of this wave in swizzled LDS tile) @ Wf
__device__ __forceinline__ void mfma_stage(const unsigned short* __restrict__ Alds,
                                           const bf16x8* __restrict__ Wf,
                                           int arow, int lane, int quad, f32x4* acc) {
#pragma unroll
  for (int c = 0; c < 8; ++c) acc[c] = (f32x4){0.f, 0.f, 0.f, 0.f};
#pragma unroll
  for (int t = 0; t < 4; ++t) {
    bf16x8 a = *(const bf16x8*)&Alds[lofs(arow, t * 32 + quad * 8)];
#pragma unroll
    for (int c = 0; c < 8; ++c)
      acc[c] = __builtin_amdgcn_mfma_f32_16x16x32_bf16(a, Wf[(t * 8 + c) * 64 + lane], acc[c], 0, 0, 0);
  }
}

// ---------------- GEMM: A(fp32)[nrows,128] @ Wp -> bf16 out (no bias/act) ----------------

__global__ __launch_bounds__(256) void gemm_conv(const float* __restrict__ A,
                                                 const unsigned short* __restrict__ Wp,
                                                 unsigned short* __restrict__ out, int nrows) {
  __shared__ __align__(16) unsigned short Al[64 * HH];
  const int tid = threadIdx.x;
  const int row0 = blockIdx.x * 64;

  for (int i = tid; i < 2048; i += 256) {
    int r = i >> 5, c = (i & 31) << 2;
    int gr = row0 + r;
    float4 v = make_float4(0.f, 0.f, 0.f, 0.f);
    if (gr < nrows) v = *(const float4*)(A + (size_t)gr * HH + c);
    ushort4 o;
    o.x = f2b(v.x); o.y = f2b(v.y); o.z = f2b(v.z); o.w = f2b(v.w);
    *(ushort4*)&Al[lofs(r, c)] = o;
  }
  __syncthreads();

  const int lane = tid & 63, wave = tid >> 6;
  const int m = lane & 15, quad = lane >> 4;
  const int arow = wave * 16 + m;

  f32x4 acc[8];
  mfma_stage(Al, (const bf16x8*)Wp, arow, lane, quad, acc);

#pragma unroll
  for (int c = 0; c < 8; ++c) {
    int col = c * 16 + m;
#pragma unroll
    for (int g = 0; g < 4; ++g) {
      int row = row0 + wave * 16 + quad * 4 + g;
      if (row < nrows) out[(size_t)row * HH + col] = f2b(acc[c][g]);
    }
  }
}

// ---------------- agg: one wave per node (max gather parallelism) ----------------
// out = leaky(sum norm*h[src] + self*dinv^2 + bias (+res fp32))  [fp32]

template <int RES>
__global__ __launch_bounds__(256) void agg_kernel(const unsigned short* __restrict__ h,
                                                  const int* __restrict__ rowptr,
                                                  const int2* __restrict__ csr,
                                                  const float* __restrict__ dinv,
                                                  const float* __restrict__ bias,
                                                  const float* __restrict__ res,
                                                  float* __restrict__ out, int n) {
  int node = blockIdx.x * 4 + (threadIdx.x >> 6);
  if (node >= n) return;
  int lane = threadIdx.x & 63;
  int c = lane << 1;
  int j = rowptr[node], end = rowptr[node + 1];
  float ax = 0.f, ay = 0.f;
  for (; j + 4 <= end; j += 4) {
    int2 e0 = csr[j], e1 = csr[j + 1], e2 = csr[j + 2], e3 = csr[j + 3];
    ushort2 r0 = *(const ushort2*)(h + (size_t)e0.x * HH + c);
    ushort2 r1 = *(const ushort2*)(h + (size_t)e1.x * HH + c);
    ushort2 r2 = *(const ushort2*)(h + (size_t)e2.x * HH + c);
    ushort2 r3 = *(const ushort2*)(h + (size_t)e3.x * HH + c);
    float n0 = __int_as_float(e0.y), n1 = __int_as_float(e1.y);
    float n2 = __int_as_float(e2.y), n3 = __int_as_float(e3.y);
    ax = fmaf(b2f(r0.x), n0, ax); ay = fmaf(b2f(r0.y), n0, ay);
    ax = fmaf(b2f(r1.x), n1, ax); ay = fmaf(b2f(r1.y), n1, ay);
    ax = fmaf(b2f(r2.x), n2, ax); ay = fmaf(b2f(r2.y), n2, ay);
    ax = fmaf(b2f(r3.x), n3, ax); ay = fmaf(b2f(r3.y), n3, ay);
  }
  for (; j < end; ++j) {
    int2 e0 = csr[j];
    float n0 = __int_as_float(e0.y);
    ushort2 r0 = *(const ushort2*)(h + (size_t)e0.x * HH + c);
    ax = fmaf(b2f(r0.x), n0, ax); ay = fmaf(b2f(r0.y), n0, ay);
  }
  float di = dinv[node], d2 = di * di;
  ushort2 hs = *(const ushort2*)(h + (size_t)node * HH + c);
  float2 b = *(const float2*)(bias + c);
  float ox = ax + b2f(hs.x) * d2 + b.x;
  float oy = ay + b2f(hs.y) * d2 + b.y;
  if (RES) {
    float2 r = *(const float2*)(res + (size_t)node * HH + c);
    ox += r.x; oy += r.y;
  }
  ox = lrelu(ox); oy = lrelu(oy);
  *(float2*)(out + (size_t)node * HH + c) = make_float2(ox, oy);
}

// ---------------- fusedMLP: 4 GEMM chain, intermediates in LDS ----------------
// stage A:  Al = bf16(f2)                       [from f2 fp32 global]
// stage 1:  m  = leaky(f2@Wm1+bm1)      -> Bl
// stage 2:  h3 = leaky(m@Wm2+bm2+f2_fp32); p = 0.5*(h3+gen) -> Al
// stage 3:  q  = leaky(p@Wp1+bp1)       -> Bl
// stage 4:  out= leaky(q@Wp2+bp2)       -> fp32 global
// __syncthreads() at every LDS write->read boundary (cross-lane RAW; r6/r7 lesson).

__global__ __launch_bounds__(256) void fusedMLP(const float* __restrict__ f2,
                                                const unsigned short* __restrict__ Wm1p,
                                                const unsigned short* __restrict__ Wm2p,
                                                const unsigned short* __restrict__ Wp1p,
                                                const unsigned short* __restrict__ Wp2p,
                                                const float* __restrict__ bm1,
                                                const float* __restrict__ bm2,
                                                const float* __restrict__ bp1,
                                                const float* __restrict__ bp2,
                                                const float* __restrict__ gen,
                                                float* __restrict__ out, int n) {
  __shared__ __align__(16) unsigned short Al[64 * HH];
  __shared__ __align__(16) unsigned short Bl[64 * HH];
  const int tid = threadIdx.x;
  const int row0 = blockIdx.x * 64;

  for (int i = tid; i < 2048; i += 256) {
    int r = i >> 5, c = (i & 31) << 2;
    int gr = row0 + r;
    float4 v = make_float4(0.f, 0.f, 0.f, 0.f);
    if (gr < n) v = *(const float4*)(f2 + (size_t)gr * HH + c);
    ushort4 o;
    o.x = f2b(v.x); o.y = f2b(v.y); o.z = f2b(v.z); o.w = f2b(v.w);
    *(ushort4*)&Al[lofs(r, c)] = o;
  }
  __syncthreads();

  const int lane = tid & 63, wave = tid >> 6;
  const int m = lane & 15, quad = lane >> 4;
  const int arow = wave * 16 + m;
  f32x4 acc[8];

  // ---- stage 1 ----
  mfma_stage(Al, (const bf16x8*)Wm1p, arow, lane, quad, acc);
#pragma unroll
  for (int cc = 0; cc < 8; ++cc) {
    int col = cc * 16 + m;
    float b1 = bm1[col];
#pragma unroll
    for (int g = 0; g < 4; ++g) {
      int lrow = wave * 16 + quad * 4 + g;
      Bl[lofs(lrow, col)] = f2b(lrelu(acc[cc][g] + b1));
    }
  }
  __syncthreads();

  // ---- stage 2 ----
  mfma_stage(Bl, (const bf16x8*)Wm2p, arow, lane, quad, acc);
#pragma unroll
  for (int cc = 0; cc < 8; ++cc) {
    int col = cc * 16 + m;
    float b2 = bm2[col];
#pragma unroll
    for (int g = 0; g < 4; ++g) {
      int lrow = wave * 16 + quad * 4 + g;
      int row = row0 + lrow;
      float f2v = 0.f, gv = 0.f;
      if (row < n) {
        f2v = f2[(size_t)row * HH + col];
        gv = gen[(size_t)row * HH + col];
      }
      float v = lrelu(acc[cc][g] + b2 + f2v);
      Al[lofs(lrow, col)] = f2b(0.5f * (v + gv));
    }
  }
  __syncthreads();

  // ---- stage 3 ----
  mfma_stage(Al, (const bf16x8*)Wp1p, arow, lane, quad, acc);
#pragma unroll
  for (int cc = 0; cc < 8; ++cc) {
    int col = cc * 16 + m;
    float b3 = bp1[col];
#pragma unroll
    for (int g = 0; g < 4; ++g) {
      int lrow = wave * 16 + quad * 4 + g;
      Bl[lofs(lrow, col)] = f2b(lrelu(acc[cc][g] + b3));
    }
  }
  __syncthreads();

  // ---- stage 4 ----
  mfma_stage(Bl, (const bf16x8*)Wp2p, arow, lane, quad, acc);
#pragma unroll
  for (int cc = 0; cc < 8; ++cc) {
    int col = cc * 16 + m;
    float b4 = bp2[col];
#pragma unroll
    for (int g = 0; g < 4; ++g) {
      int row = row0 + wave * 16 + quad * 4 + g;
      if (row < n) out[(size_t)row * HH + col] = lrelu(acc[cc][g] + b4);
    }
  }
}

// ---------------- launcher ----------------

extern "C" void kernel_launch(void* const* d_in, const int* in_sizes, int n_in,
                              void* d_out, int out_size, void* d_ws, size_t ws_size,
                              hipStream_t stream) {
  const float* x   = (const float*)d_in[0];
  const int* ei    = (const int*)d_in[1];
  const float* gen = (const float*)d_in[2];
  const float* Wc1 = (const float*)d_in[3];
  const float* bc1 = (const float*)d_in[4];
  const float* Wc2 = (const float*)d_in[5];
  const float* bc2 = (const float*)d_in[6];
  const float* Wm1 = (const float*)d_in[7];
  const float* bm1 = (const float*)d_in[8];
  const float* Wm2 = (const float*)d_in[9];
  const float* bm2 = (const float*)d_in[10];
  const float* Wp1 = (const float*)d_in[11];
  const float* bp1 = (const float*)d_in[12];
  const float* Wp2 = (const float*)d_in[13];
  const float* bp2 = (const float*)d_in[14];

  const int N = in_sizes[0] / HH;
  const int E = in_sizes[1] / 2;
  const int* src = ei;
  const int* dst = ei + E;

  char* ws = (char*)d_ws;
  size_t off = 0;
  auto alloc = [&](size_t bytes) { void* p = ws + off; off += (bytes + 255) & ~(size_t)255; return p; };
  float* dinv            = (float*)alloc((size_t)N * 4);
  int*   rowptr          = (int*)  alloc((size_t)(N + 1) * 4);
  int*   cursor          = (int*)  alloc((size_t)N * 4);
  int*   bsum            = (int*)  alloc((size_t)64 * 4);
  int2*  csr             = (int2*) alloc((size_t)E * 8);
  unsigned short* h_bf   = (unsigned short*)alloc((size_t)N * HH * 2);
  unsigned short* t2_bf  = (unsigned short*)alloc((size_t)N * HH * 2);
  float* f1_f32          = (float*)alloc((size_t)N * HH * 4);
  float* f2_f32          = (float*)alloc((size_t)N * HH * 4);
  unsigned short* packed = (unsigned short*)alloc((size_t)6 * 16384 * 2);
  float* fOut = (float*)d_out;

  const int gblocks = (N + 63) / 64;
  const int eblocks = (E + 255) / 256;
  const int ablocks = (N + 3) / 4;
  const int sblocks = (N + 1023) / 1024;  // <= 64 for N <= 65536

  // weight packing
  pack_kernel<<<dim3(64, 6), 256, 0, stream>>>(Wc1, Wc2, Wm1, Wm2, Wp1, Wp2, packed);

  // CSR build
  hipMemsetAsync(cursor, 0, (size_t)N * 4, stream);
  count_kernel<<<eblocks, 256, 0, stream>>>(dst, cursor, E);
  scan1_kernel<<<sblocks, 1024, 0, stream>>>(cursor, rowptr, bsum, dinv, N);
  scan2_kernel<<<1, 64, 0, stream>>>(bsum, sblocks, rowptr, N, E);
  scan3_kernel<<<sblocks, 1024, 0, stream>>>(rowptr, bsum, N);
  fill_kernel<<<eblocks, 256, 0, stream>>>(src, dst, rowptr, cursor, dinv, csr, E);

  // conv1: h_bf = bf16(x @ Wc1)
  gemm_conv<<<gblocks, 256, 0, stream>>>(x, packed + 0 * 16384, h_bf, N);
  // agg1: f1 = leaky(agg(h_bf)+self+bc1)  [fp32]
  agg_kernel<0><<<ablocks, 256, 0, stream>>>(h_bf, rowptr, csr, dinv, bc1, nullptr, f1_f32, N);
  // conv2: t2 = bf16(f1 @ Wc2)
  gemm_conv<<<gblocks, 256, 0, stream>>>(f1_f32, packed + 1 * 16384, t2_bf, N);
  // agg2: f2 = leaky(agg(t2)+self+bc2+f1)  [fp32]
  agg_kernel<1><<<ablocks, 256, 0, stream>>>(t2_bf, rowptr, csr, dinv, bc2, f1_f32, f2_f32, N);
  // fusedMLP: MLP + interp + proj -> d_out
  fusedMLP<<<gblocks, 256, 0, stream>>>(f2_f32,
                                        packed + 2 * 16384, packed + 3 * 16384,
                                        packed + 4 * 16384, packed + 5 * 16384,
                                        bm1, bm2, bp1, bp2, gen, fOut, N);
}

// Round 10
// 308.555 us; speedup vs baseline: 1.1813x; 1.0906x over previous
//
#include <hip/hip_runtime.h>
#include <cstdint>
#include <cstddef>

#define HH 128
#define SLOPE 0.01f

typedef __attribute__((ext_vector_type(8))) __bf16 bf16x8;
typedef __attribute__((ext_vector_type(4))) float f32x4;

__device__ __forceinline__ float lrelu(float x) { return x >= 0.f ? x : SLOPE * x; }
__device__ __forceinline__ unsigned short f2b(float f) {
  union { float f; unsigned u; } v; v.f = f;
  unsigned r = v.u + 0x7fffu + ((v.u >> 16) & 1u);  // round-to-nearest-even
  return (unsigned short)(r >> 16);
}
__device__ __forceinline__ float b2f(unsigned short u) {
  union { unsigned u; float f; } v; v.u = ((unsigned)u) << 16; return v.f;
}

// LDS tile layout with XOR swizzle: element (r,k) of a 64x128 bf16 tile lives at
// lofs(r,k). 16B chunks (8 ushorts) stay contiguous; chunk index ^= (r&15).
__device__ __forceinline__ int lofs(int r, int k) {
  return (r << 7) + ((((k >> 3) ^ r) & 15) << 3) + (k & 7);
}

// ---------------- CSR build ----------------

__global__ __launch_bounds__(256) void count_kernel(const int* __restrict__ dst,
                                                    int* __restrict__ cnt, int nE) {
  int e = blockIdx.x * 256 + threadIdx.x;
  if (e < nE) atomicAdd(&cnt[dst[e]], 1);
}

__global__ __launch_bounds__(1024) void scan1_kernel(int* __restrict__ cnt,
                                                     int* __restrict__ rowptr,
                                                     int* __restrict__ bsum,
                                                     float* __restrict__ dinv, int n) {
  __shared__ int wsum[16];
  const int tid = threadIdx.x;
  const int lane = tid & 63, wid = tid >> 6;
  int i = blockIdx.x * 1024 + tid;
  int v = (i < n) ? cnt[i] : 0;
  int x = v;
#pragma unroll
  for (int off = 1; off < 64; off <<= 1) {
    int y = __shfl_up(x, off, 64);
    if (lane >= off) x += y;
  }
  if (lane == 63) wsum[wid] = x;
  __syncthreads();
  if (tid == 0) {
    int s = 0;
#pragma unroll
    for (int w = 0; w < 16; ++w) { int t = wsum[w]; wsum[w] = s; s += t; }
    bsum[blockIdx.x] = s;
  }
  __syncthreads();
  if (i < n) {
    rowptr[i] = wsum[wid] + x - v;  // local exclusive
    dinv[i] = rsqrtf((float)v + 1.0f);
    cnt[i] = 0;
  }
}

__global__ __launch_bounds__(64) void scan2_kernel(int* __restrict__ bsum, int nb,
                                                   int* __restrict__ rowptr, int n, int E) {
  int lane = threadIdx.x;
  int v = (lane < nb) ? bsum[lane] : 0;
  int x = v;
#pragma unroll
  for (int off = 1; off < 64; off <<= 1) {
    int y = __shfl_up(x, off, 64);
    if (lane >= off) x += y;
  }
  if (lane < nb) bsum[lane] = x - v;  // exclusive
  if (lane == 0) rowptr[n] = E;
}

__global__ __launch_bounds__(1024) void scan3_kernel(int* __restrict__ rowptr,
                                                     const int* __restrict__ bsum, int n) {
  int i = blockIdx.x * 1024 + threadIdx.x;
  if (i < n) rowptr[i] += bsum[blockIdx.x];
}

// csr entry: .x = src node, .y = norm (float bits)
__global__ __launch_bounds__(256) void fill_kernel(const int* __restrict__ src,
                                                   const int* __restrict__ dst,
                                                   const int* __restrict__ rowptr,
                                                   int* __restrict__ cursor,
                                                   const float* __restrict__ dinv,
                                                   int2* __restrict__ csr, int nE) {
  int e = blockIdx.x * 256 + threadIdx.x;
  if (e >= nE) return;
  int d = dst[e], s = src[e];
  int pos = rowptr[d] + atomicAdd(&cursor[d], 1);
  int2 ent;
  ent.x = s;
  ent.y = __float_as_int(dinv[s] * dinv[d]);
  csr[pos] = ent;
}

// ---------------- weight pack: B-fragment order for mfma 16x16x32 ----------------
__global__ __launch_bounds__(256) void pack_kernel(const float* W0, const float* W1,
                                                   const float* W2, const float* W3,
                                                   const float* W4, const float* W5,
                                                   unsigned short* __restrict__ out) {
  const float* Ws[6] = {W0, W1, W2, W3, W4, W5};
  const float* W = Ws[blockIdx.y];
  int f = blockIdx.x * 256 + threadIdx.x;  // 0..16383
  int j = f & 7, L = (f >> 3) & 63, c = (f >> 9) & 7, t = f >> 12;
  int k = t * 32 + (L >> 4) * 8 + j;
  int n = c * 16 + (L & 15);
  out[(size_t)blockIdx.y * 16384 + f] = f2b(W[k * HH + n]);
}

// ---------------- shared device helpers ----------------

__device__ __forceinline__ void mfma_stage(const unsigned short* __restrict__ Alds,
                                           const bf16x8* __restrict__ Wf,
                                           int arow, int lane, int quad, f32x4* acc) {
#pragma unroll
  for (int c = 0; c < 8; ++c) acc[c] = (f32x4){0.f, 0.f, 0.f, 0.f};
#pragma unroll
  for (int t = 0; t < 4; ++t) {
    bf16x8 a = *(const bf16x8*)&Alds[lofs(arow, t * 32 + quad * 8)];
#pragma unroll
    for (int c = 0; c < 8; ++c)
      acc[c] = __builtin_amdgcn_mfma_f32_16x16x32_bf16(a, Wf[(t * 8 + c) * 64 + lane], acc[c], 0, 0, 0);
  }
}

// ---------------- GEMM: A(fp32)[nrows,128] @ Wp -> bf16 out ----------------

__global__ __launch_bounds__(256) void gemm_conv(const float* __restrict__ A,
                                                 const unsigned short* __restrict__ Wp,
                                                 unsigned short* __restrict__ out, int nrows) {
  __shared__ __align__(16) unsigned short Al[64 * HH];
  const int tid = threadIdx.x;
  const int row0 = blockIdx.x * 64;

  for (int i = tid; i < 2048; i += 256) {
    int r = i >> 5, c = (i & 31) << 2;
    int gr = row0 + r;
    float4 v = make_float4(0.f, 0.f, 0.f, 0.f);
    if (gr < nrows) v = *(const float4*)(A + (size_t)gr * HH + c);
    ushort4 o;
    o.x = f2b(v.x); o.y = f2b(v.y); o.z = f2b(v.z); o.w = f2b(v.w);
    *(ushort4*)&Al[lofs(r, c)] = o;
  }
  __syncthreads();

  const int lane = tid & 63, wave = tid >> 6;
  const int m = lane & 15, quad = lane >> 4;
  const int arow = wave * 16 + m;

  f32x4 acc[8];
  mfma_stage(Al, (const bf16x8*)Wp, arow, lane, quad, acc);

#pragma unroll
  for (int c = 0; c < 8; ++c) {
    int col = c * 16 + m;
#pragma unroll
    for (int g = 0; g < 4; ++g) {
      int row = row0 + wave * 16 + quad * 4 + g;
      if (row < nrows) out[(size_t)row * HH + col] = f2b(acc[c][g]);
    }
  }
}

// ---------------- agg: one wave per node ----------------
// out = leaky(sum norm*h[src] + self*dinv^2 + bias (+res fp32)); fp32 or bf16 out.

template <int RES, int OUTBF>
__global__ __launch_bounds__(256) void agg_kernel(const unsigned short* __restrict__ h,
                                                  const int* __restrict__ rowptr,
                                                  const int2* __restrict__ csr,
                                                  const float* __restrict__ dinv,
                                                  const float* __restrict__ bias,
                                                  const float* __restrict__ res,
                                                  void* __restrict__ outv, int n) {
  int node = blockIdx.x * 4 + (threadIdx.x >> 6);
  if (node >= n) return;
  int lane = threadIdx.x & 63;
  int c = lane << 1;
  int j = rowptr[node], end = rowptr[node + 1];
  float ax = 0.f, ay = 0.f;
  // 8-deep unroll: 8 outstanding gather loads per lane
  for (; j + 8 <= end; j += 8) {
    int2 e[8];
    ushort2 r[8];
#pragma unroll
    for (int q = 0; q < 8; ++q) e[q] = csr[j + q];
#pragma unroll
    for (int q = 0; q < 8; ++q) r[q] = *(const ushort2*)(h + (size_t)e[q].x * HH + c);
#pragma unroll
    for (int q = 0; q < 8; ++q) {
      float nv = __int_as_float(e[q].y);
      ax = fmaf(b2f(r[q].x), nv, ax); ay = fmaf(b2f(r[q].y), nv, ay);
    }
  }
  for (; j + 2 <= end; j += 2) {
    int2 e0 = csr[j], e1 = csr[j + 1];
    ushort2 r0 = *(const ushort2*)(h + (size_t)e0.x * HH + c);
    ushort2 r1 = *(const ushort2*)(h + (size_t)e1.x * HH + c);
    float n0 = __int_as_float(e0.y), n1 = __int_as_float(e1.y);
    ax = fmaf(b2f(r0.x), n0, ax); ay = fmaf(b2f(r0.y), n0, ay);
    ax = fmaf(b2f(r1.x), n1, ax); ay = fmaf(b2f(r1.y), n1, ay);
  }
  if (j < end) {
    int2 e0 = csr[j];
    float n0 = __int_as_float(e0.y);
    ushort2 r0 = *(const ushort2*)(h + (size_t)e0.x * HH + c);
    ax = fmaf(b2f(r0.x), n0, ax); ay = fmaf(b2f(r0.y), n0, ay);
  }
  float di = dinv[node], d2 = di * di;
  ushort2 hs = *(const ushort2*)(h + (size_t)node * HH + c);
  float2 b = *(const float2*)(bias + c);
  float ox = ax + b2f(hs.x) * d2 + b.x;
  float oy = ay + b2f(hs.y) * d2 + b.y;
  if (RES) {
    float2 r = *(const float2*)(res + (size_t)node * HH + c);
    ox += r.x; oy += r.y;
  }
  ox = lrelu(ox); oy = lrelu(oy);
  if (OUTBF) {
    ushort2 o; o.x = f2b(ox); o.y = f2b(oy);
    *(ushort2*)((unsigned short*)outv + (size_t)node * HH + c) = o;
  } else {
    *(float2*)((float*)outv + (size_t)node * HH + c) = make_float2(ox, oy);
  }
}

// ---------------- fusedMLP: 4 GEMM chain, everything in LDS ----------------
// prologue: Al = f2(bf16), Cl = bf16(gen)   [all global reads up front]
// stage 1:  m  = leaky(f2@Wm1+bm1)                      -> Bl
// stage 2:  h3 = leaky(m@Wm2+bm2 + b2f(Al)); p = 0.5*(h3 + b2f(Cl)) -> Al
// stage 3:  q  = leaky(p@Wp1+bp1)                       -> Bl
// stage 4:  out= leaky(q@Wp2+bp2)                       -> fp32 global
// __syncthreads() at every LDS write->read boundary (cross-lane RAW; r6/r7 lesson).

__global__ __launch_bounds__(256) void fusedMLP(const unsigned short* __restrict__ f2bf,
                                                const unsigned short* __restrict__ Wm1p,
                                                const unsigned short* __restrict__ Wm2p,
                                                const unsigned short* __restrict__ Wp1p,
                                                const unsigned short* __restrict__ Wp2p,
                                                const float* __restrict__ bm1,
                                                const float* __restrict__ bm2,
                                                const float* __restrict__ bp1,
                                                const float* __restrict__ bp2,
                                                const float* __restrict__ gen,
                                                float* __restrict__ out, int n) {
  __shared__ __align__(16) unsigned short Al[64 * HH];
  __shared__ __align__(16) unsigned short Bl[64 * HH];
  __shared__ __align__(16) unsigned short Cl[64 * HH];
  const int tid = threadIdx.x;
  const int row0 = blockIdx.x * 64;

  // stage f2 (bf16, 16B chunks land in exactly one swizzled chunk)
  for (int i = tid; i < 1024; i += 256) {
    int r = i >> 4, k = (i & 15) << 3;
    int gr = row0 + r;
    float4 v = make_float4(0.f, 0.f, 0.f, 0.f);
    if (gr < n) v = *(const float4*)(f2bf + (size_t)gr * HH + k);
    *(float4*)&Al[lofs(r, k)] = v;
  }
  // stage gen (fp32 -> bf16)
  for (int i = tid; i < 2048; i += 256) {
    int r = i >> 5, c = (i & 31) << 2;
    int gr = row0 + r;
    float4 v = make_float4(0.f, 0.f, 0.f, 0.f);
    if (gr < n) v = *(const float4*)(gen + (size_t)gr * HH + c);
    ushort4 o;
    o.x = f2b(v.x); o.y = f2b(v.y); o.z = f2b(v.z); o.w = f2b(v.w);
    *(ushort4*)&Cl[lofs(r, c)] = o;
  }
  __syncthreads();

  const int lane = tid & 63, wave = tid >> 6;
  const int m = lane & 15, quad = lane >> 4;
  const int arow = wave * 16 + m;
  f32x4 acc[8];

  // ---- stage 1 ----
  mfma_stage(Al, (const bf16x8*)Wm1p, arow, lane, quad, acc);
#pragma unroll
  for (int cc = 0; cc < 8; ++cc) {
    int col = cc * 16 + m;
    float b1 = bm1[col];
#pragma unroll
    for (int g = 0; g < 4; ++g) {
      int lrow = wave * 16 + quad * 4 + g;
      Bl[lofs(lrow, col)] = f2b(lrelu(acc[cc][g] + b1));
    }
  }
  __syncthreads();

  // ---- stage 2 (residual + interp, all LDS) ----
  mfma_stage(Bl, (const bf16x8*)Wm2p, arow, lane, quad, acc);
#pragma unroll
  for (int cc = 0; cc < 8; ++cc) {
    int col = cc * 16 + m;
    float b2 = bm2[col];
#pragma unroll
    for (int g = 0; g < 4; ++g) {
      int lrow = wave * 16 + quad * 4 + g;
      float f2v = b2f(Al[lofs(lrow, col)]);
      float gv = b2f(Cl[lofs(lrow, col)]);
      float v = lrelu(acc[cc][g] + b2 + f2v);
      Al[lofs(lrow, col)] = f2b(0.5f * (v + gv));
    }
  }
  __syncthreads();

  // ---- stage 3 ----
  mfma_stage(Al, (const bf16x8*)Wp1p, arow, lane, quad, acc);
#pragma unroll
  for (int cc = 0; cc < 8; ++cc) {
    int col = cc * 16 + m;
    float b3 = bp1[col];
#pragma unroll
    for (int g = 0; g < 4; ++g) {
      int lrow = wave * 16 + quad * 4 + g;
      Bl[lofs(lrow, col)] = f2b(lrelu(acc[cc][g] + b3));
    }
  }
  __syncthreads();

  // ---- stage 4 ----
  mfma_stage(Bl, (const bf16x8*)Wp2p, arow, lane, quad, acc);
#pragma unroll
  for (int cc = 0; cc < 8; ++cc) {
    int col = cc * 16 + m;
    float b4 = bp2[col];
#pragma unroll
    for (int g = 0; g < 4; ++g) {
      int row = row0 + wave * 16 + quad * 4 + g;
      if (row < n) out[(size_t)row * HH + col] = lrelu(acc[cc][g] + b4);
    }
  }
}

// ---------------- launcher ----------------

extern "C" void kernel_launch(void* const* d_in, const int* in_sizes, int n_in,
                              void* d_out, int out_size, void* d_ws, size_t ws_size,
                              hipStream_t stream) {
  const float* x   = (const float*)d_in[0];
  const int* ei    = (const int*)d_in[1];
  const float* gen = (const float*)d_in[2];
  const float* Wc1 = (const float*)d_in[3];
  const float* bc1 = (const float*)d_in[4];
  const float* Wc2 = (const float*)d_in[5];
  const float* bc2 = (const float*)d_in[6];
  const float* Wm1 = (const float*)d_in[7];
  const float* bm1 = (const float*)d_in[8];
  const float* Wm2 = (const float*)d_in[9];
  const float* bm2 = (const float*)d_in[10];
  const float* Wp1 = (const float*)d_in[11];
  const float* bp1 = (const float*)d_in[12];
  const float* Wp2 = (const float*)d_in[13];
  const float* bp2 = (const float*)d_in[14];

  const int N = in_sizes[0] / HH;
  const int E = in_sizes[1] / 2;
  const int* src = ei;
  const int* dst = ei + E;

  char* ws = (char*)d_ws;
  size_t off = 0;
  auto alloc = [&](size_t bytes) { void* p = ws + off; off += (bytes + 255) & ~(size_t)255; return p; };
  float* dinv            = (float*)alloc((size_t)N * 4);
  int*   rowptr          = (int*)  alloc((size_t)(N + 1) * 4);
  int*   cursor          = (int*)  alloc((size_t)N * 4);
  int*   bsum            = (int*)  alloc((size_t)64 * 4);
  int2*  csr             = (int2*) alloc((size_t)E * 8);
  unsigned short* h_bf   = (unsigned short*)alloc((size_t)N * HH * 2);
  unsigned short* t2_bf  = (unsigned short*)alloc((size_t)N * HH * 2);
  unsigned short* f2_bf  = (unsigned short*)alloc((size_t)N * HH * 2);
  float* f1_f32          = (float*)alloc((size_t)N * HH * 4);
  unsigned short* packed = (unsigned short*)alloc((size_t)6 * 16384 * 2);
  float* fOut = (float*)d_out;

  const int gblocks = (N + 63) / 64;
  const int eblocks = (E + 255) / 256;
  const int ablocks = (N + 3) / 4;
  const int sblocks = (N + 1023) / 1024;  // <= 64 for N <= 65536

  // weight packing
  pack_kernel<<<dim3(64, 6), 256, 0, stream>>>(Wc1, Wc2, Wm1, Wm2, Wp1, Wp2, packed);

  // CSR build
  hipMemsetAsync(cursor, 0, (size_t)N * 4, stream);
  count_kernel<<<eblocks, 256, 0, stream>>>(dst, cursor, E);
  scan1_kernel<<<sblocks, 1024, 0, stream>>>(cursor, rowptr, bsum, dinv, N);
  scan2_kernel<<<1, 64, 0, stream>>>(bsum, sblocks, rowptr, N, E);
  scan3_kernel<<<sblocks, 1024, 0, stream>>>(rowptr, bsum, N);
  fill_kernel<<<eblocks, 256, 0, stream>>>(src, dst, rowptr, cursor, dinv, csr, E);

  // conv1: h_bf = bf16(x @ Wc1)
  gemm_conv<<<gblocks, 256, 0, stream>>>(x, packed + 0 * 16384, h_bf, N);
  // agg1: f1 = leaky(agg(h_bf)+self+bc1)  [fp32]
  agg_kernel<0, 0><<<ablocks, 256, 0, stream>>>(h_bf, rowptr, csr, dinv, bc1, nullptr, f1_f32, N);
  // conv2: t2 = bf16(f1 @ Wc2)
  gemm_conv<<<gblocks, 256, 0, stream>>>(f1_f32, packed + 1 * 16384, t2_bf, N);
  // agg2: f2 = leaky(agg(t2)+self+bc2+f1)  [bf16 — only consumed as bf16]
  agg_kernel<1, 1><<<ablocks, 256, 0, stream>>>(t2_bf, rowptr, csr, dinv, bc2, f1_f32, f2_bf, N);
  // fusedMLP: MLP + interp + proj -> d_out (all intermediates in LDS)
  fusedMLP<<<gblocks, 256, 0, stream>>>(f2_bf,
                                        packed + 2 * 16384, packed + 3 * 16384,
                                        packed + 4 * 16384, packed + 5 * 16384,
                                        bm1, bm2, bp1, bp2, gen, fOut, N);
}